// Round 8
// baseline (216.005 us; speedup 1.0000x reference)
//
#include <hip/hip_runtime.h>
#include <cstdint>
#include <cstddef>

typedef _Float16 half_t;
typedef half_t h8 __attribute__((ext_vector_type(8)));
typedef half_t h4 __attribute__((ext_vector_type(4)));
typedef float f4 __attribute__((ext_vector_type(4)));
typedef float f16v __attribute__((ext_vector_type(16)));
typedef unsigned int u32;

static constexpr int S_LEN  = 4096;
static constexpr int DMODEL = 512;
static constexpr int NH     = 8;
static constexpr int HD     = 64;
static constexpr int BATCH  = 2;
static constexpr int MTOK   = BATCH * S_LEN;   // 8192

// 0.125 (1/sqrt(64)) * log2(e): folded into Wq so softmax is pure exp2
#define QSCALE 0.18033688011112043f

// ---------------- async global->LDS (16B per lane) ----------------
__device__ __forceinline__ void g2lds16(const void* g, void* l) {
    __builtin_amdgcn_global_load_lds(
        (const __attribute__((address_space(1))) u32*)(uintptr_t)g,
        (__attribute__((address_space(3))) u32*)(u32)(uintptr_t)l,
        16, 0, 0);
}

__device__ __forceinline__ f4 mfma16(h8 a, h8 b, f4 c) {
    return __builtin_amdgcn_mfma_f32_16x16x32_f16(a, b, c, 0, 0, 0);
}

__device__ __forceinline__ f16v mfma32(h8 a, h8 b, f16v c) {
    return __builtin_amdgcn_mfma_f32_32x32x16_f16(a, b, c, 0, 0, 0);
}

// pack two f32 -> one dword of 2 fp16 (v_cvt_pkrtz_f16_f32)
__device__ __forceinline__ u32 pkrtz(float a, float b) {
#if __has_builtin(__builtin_amdgcn_cvt_pkrtz)
    auto r = __builtin_amdgcn_cvt_pkrtz(a, b);   // __fp16 ext_vector(2)
    return __builtin_bit_cast(u32, r);
#else
    union { half_t h[2]; u32 u; } x;
    x.h[0] = (half_t)a; x.h[1] = (half_t)b;
    return x.u;
#endif
}

// v_permlane32_swap: swaps a's upper 32 lanes with b's lower 32 lanes.
__device__ __forceinline__ void plswap(u32 a, u32 b, u32& lo, u32& hi_, int hi) {
#if __has_builtin(__builtin_amdgcn_permlane32_swap)
    auto r = __builtin_amdgcn_permlane32_swap(a, b, false, false);
    lo = (u32)r[0]; hi_ = (u32)r[1];
#else
    u32 ta = __shfl_xor(a, 32);
    u32 tb = __shfl_xor(b, 32);
    lo  = hi ? tb : a;
    hi_ = hi ? b  : ta;
#endif
}

// ---------------- fp32 -> fp16 converts (X + 4 weights, one launch) --------
__global__ void cvt_all(const float* __restrict__ X,
                        const float* __restrict__ w0, const float* __restrict__ w1,
                        const float* __restrict__ w2, const float* __restrict__ w3,
                        half_t* __restrict__ Xh,
                        half_t* __restrict__ o0, half_t* __restrict__ o1,
                        half_t* __restrict__ o2, half_t* __restrict__ o3) {
    int bx = blockIdx.x;
    const float* in;
    half_t* out;
    float s = 1.0f;
    int i;
    if (bx < 2048) {                       // X: 8192*512 elems
        in = X; out = Xh;
        i = (bx * 256 + threadIdx.x) * 8;
    } else {                               // weights: 512*512 each
        int y = (bx - 2048) >> 7;          // /128
        in  = (y==0) ? w0 : (y==1) ? w1 : (y==2) ? w2 : w3;
        out = (y==0) ? o0 : (y==1) ? o1 : (y==2) ? o2 : o3;
        if (y == 0) s = QSCALE;
        i = (((bx - 2048) & 127) * 256 + threadIdx.x) * 8;
    }
    const float4* p = (const float4*)(in + i);
    float4 a = p[0], b = p[1];
    h8 h;
    h[0]=(half_t)(a.x*s); h[1]=(half_t)(a.y*s); h[2]=(half_t)(a.z*s); h[3]=(half_t)(a.w*s);
    h[4]=(half_t)(b.x*s); h[5]=(half_t)(b.y*s); h[6]=(half_t)(b.z*s); h[7]=(half_t)(b.w*s);
    *(h8*)(out + i) = h;
}

// ------- GEMM core v3: 64x128 tile, BK=64, fragment-major LDS -------
// LDS layout = MFMA fragment order: slot (frag, lane) holds the 16B that
// lane consumes -> ds_read_b128 at base+lane*16+imm (conflict-free, no VALU).
// A frags: (m16 0..3, kk 0..1, lane): A[m0+m16*16+(l&15)][kk0+kk*32+(l>>4)*8]
// B frags: (n16 0..7, kk 0..1, lane): B[n0+n16*16+(l&15)][kk0+kk*32+(l>>4)*8]
__device__ __forceinline__ void gemm_core3(const half_t* __restrict__ A,
                                           const half_t* __restrict__ B,
                                           int m0, int n0, int Kdim,
                                           half_t* As, half_t* Bs,   // [2][...]
                                           f4 (&acc)[2][4]) {
    const int tid  = threadIdx.x;
    const int lane = tid & 63;
    const int w    = tid >> 6;
    const int low  = lane & 15;
    const int quad = lane >> 4;

    f4 zero = {0.f, 0.f, 0.f, 0.f};
    #pragma unroll
    for (int i = 0; i < 2; ++i)
        #pragma unroll
        for (int j = 0; j < 4; ++j) acc[i][j] = zero;

    auto stage = [&](int kk0, int p) {
        #pragma unroll
        for (int it = 0; it < 2; ++it) {   // A: 512 chunks of 16B
            int c = tid + 256 * it;
            int row = m0 + (c >> 7) * 16 + low;
            int col = kk0 + ((c >> 6) & 1) * 32 + quad * 8;
            g2lds16(A + (size_t)row * Kdim + col, As + p * 4096 + c * 8);
        }
        #pragma unroll
        for (int it = 0; it < 4; ++it) {   // B: 1024 chunks of 16B
            int c = tid + 256 * it;
            int row = n0 + (c >> 7) * 16 + low;
            int col = kk0 + ((c >> 6) & 1) * 32 + quad * 8;
            g2lds16(B + (size_t)row * Kdim + col, Bs + p * 8192 + c * 8);
        }
    };

    stage(0, 0);
    const int T = Kdim / 64;
    const int aoff = (w >> 1) * 2048 + lane * 8;   // m16 base = (w>>1)*2
    const int boff = (w & 1) * 4096 + lane * 8;    // n16 base = (w&1)*4
    for (int t = 0; t < T; ++t) {
        __syncthreads();                    // buf t&1 staged; other buf reusable
        if (t + 1 < T) stage((t + 1) * 64, (t + 1) & 1);

        const half_t* Al = As + (t & 1) * 4096 + aoff;
        const half_t* Bl = Bs + (t & 1) * 8192 + boff;
        h8 af[2][2], bf[4][2];
        #pragma unroll
        for (int i = 0; i < 2; ++i)
            #pragma unroll
            for (int kk = 0; kk < 2; ++kk)
                af[i][kk] = *(const h8*)(Al + i * 1024 + kk * 512);
        #pragma unroll
        for (int j = 0; j < 4; ++j)
            #pragma unroll
            for (int kk = 0; kk < 2; ++kk)
                bf[j][kk] = *(const h8*)(Bl + j * 1024 + kk * 512);
        #pragma unroll
        for (int kk = 0; kk < 2; ++kk)
            #pragma unroll
            for (int i = 0; i < 2; ++i)
                #pragma unroll
                for (int j = 0; j < 4; ++j)
                    acc[i][j] = mfma16(af[i][kk], bf[j][kk], acc[i][j]);
    }
}

// Merged projections: z=0 Q, z=1 K (tokens x d), z=2 V^T (d x tokens).
__global__ __launch_bounds__(256, 3) void gemm_proj(
    const half_t* __restrict__ X,
    const half_t* __restrict__ Wq, const half_t* __restrict__ Wk, const half_t* __restrict__ Wv,
    half_t* __restrict__ Q, half_t* __restrict__ K, half_t* __restrict__ Vt) {
    __shared__ half_t As[2 * 64 * 64];
    __shared__ half_t Bs[2 * 128 * 64];
    const int z  = blockIdx.z;
    const int bx = blockIdx.x;

    const half_t *A, *B;
    int m0, n0;
    if (z < 2) {          // C = X · W^T : M=8192 tokens, N=512 d
        A = X; B = (z == 0) ? Wq : Wk;
        m0 = (bx >> 2) * 64; n0 = (bx & 3) * 128;
    } else {              // C = Wv · X^T : M=512 d, N=8192 tokens
        A = Wv; B = X;
        m0 = (bx & 7) * 64; n0 = (bx >> 3) * 128;
    }
    f4 acc[2][4];
    gemm_core3(A, B, m0, n0, DMODEL, As, Bs, acc);

    const int lane = threadIdx.x & 63;
    const int w    = threadIdx.x >> 6;
    const int quad = lane >> 4, low = lane & 15;
    const int wr = (w >> 1) * 32, wc = (w & 1) * 64;

    if (z < 2) {
        half_t* O = (z == 0) ? Q : K;
        #pragma unroll
        for (int i = 0; i < 2; ++i) {
            int mb = m0 + wr + i * 16 + quad * 4;
            #pragma unroll
            for (int j = 0; j < 4; ++j) {
                int n = n0 + wc + j * 16 + low;
                int h = n >> 6, d = n & 63;
                #pragma unroll
                for (int r = 0; r < 4; ++r) {
                    int m = mb + r;
                    int b = m >> 12, s = m & 4095;
                    size_t idx = (((size_t)(b * NH + h) << 12) + s) * 64 + d;
                    O[idx] = (half_t)acc[i][j][r];
                }
            }
        }
    } else {
        #pragma unroll
        for (int i = 0; i < 2; ++i) {
            int dgb = m0 + wr + i * 16 + quad * 4;
            #pragma unroll
            for (int j = 0; j < 4; ++j) {
                int tok = n0 + wc + j * 16 + low;
                int b = tok >> 12, s = tok & 4095;
                #pragma unroll
                for (int r = 0; r < 4; ++r) {
                    int dg = dgb + r;
                    size_t idx = (((size_t)(b * NH + (dg >> 6)) << 18)) + ((dg & 63) << 12) + s;
                    Vt[idx] = (half_t)acc[i][j][r];
                }
            }
        }
    }
}

// Output projection + bias, fp32 out [8192, 512]. 64x128 tiles.
__global__ __launch_bounds__(256, 3) void gemm_out(
    const half_t* __restrict__ A, const half_t* __restrict__ W,
    const float* __restrict__ bias, float* __restrict__ out) {
    __shared__ half_t As[2 * 64 * 64];
    __shared__ half_t Bs[2 * 128 * 64];
    const int bx = blockIdx.x;
    const int m0 = (bx >> 2) * 64;
    const int n0 = (bx & 3) * 128;
    f4 acc[2][4];
    gemm_core3(A, W, m0, n0, DMODEL, As, Bs, acc);

    const int lane = threadIdx.x & 63;
    const int w    = threadIdx.x >> 6;
    const int quad = lane >> 4, low = lane & 15;
    const int wr = (w >> 1) * 32, wc = (w & 1) * 64;

    #pragma unroll
    for (int i = 0; i < 2; ++i) {
        int mb = m0 + wr + i * 16 + quad * 4;
        #pragma unroll
        for (int j = 0; j < 4; ++j) {
            int n = n0 + wc + j * 16 + low;
            float bv = bias[n];
            #pragma unroll
            for (int r = 0; r < 4; ++r)
                out[(size_t)(mb + r) * DMODEL + n] = acc[i][j][r] + bv;
        }
    }
}

// ---------------- flash attention, 32x32 MFMA, fragment-major K/V LDS -----
// K LDS: slot (nt 0..3, ks 0..3, lane): K[k0+nt*32+(l&31)][ks*16+(l>>5)*8]
// V LDS: slot (dt 0..1, k8 0..7, lane): V[dt*32+(l&31)][k0+k8*16+(l>>5)*8]
// -> every ds_read_b128 is base+lane*16+imm: conflict-free, zero addr VALU.
// P built in-register: exp2 -> cvt_pkrtz -> permlane32_swap (no P slab).
__global__ __launch_bounds__(256, 2) void flash_attn(
    const half_t* __restrict__ Q,   // [BH][S][64]
    const half_t* __restrict__ K,   // [BH][S][64]
    const half_t* __restrict__ V,   // [BH][64][S]  (d-major)
    half_t* __restrict__ Oa) {      // [B][S][512]
    __shared__ half_t Ks[2][128 * 64];   // 2x16 KB fragment-major
    __shared__ half_t Vs[2][64 * 128];   // 2x16 KB fragment-major

    const int tid  = threadIdx.x;
    const int lane = tid & 63;
    const int w    = tid >> 6;
    const int l31  = lane & 31;
    const int hi   = lane >> 5;
    const int bh   = blockIdx.y;
    const int q0   = blockIdx.x * 128 + w * 32;

    const half_t* Qb = Q + ((size_t)bh << 18);
    const half_t* Kb = K + ((size_t)bh << 18);
    const half_t* Vb = V + ((size_t)bh << 18);

    // Q fragments (B-operand of S^T): lane holds q=q0+l31, k=ks*16+hi*8..+7
    h8 qf[4];
    #pragma unroll
    for (int ks = 0; ks < 4; ++ks)
        qf[ks] = *(const h8*)(Qb + (size_t)(q0 + l31) * 64 + ks * 16 + hi * 8);

    f16v zz;
    #pragma unroll
    for (int r = 0; r < 16; ++r) zz[r] = 0.f;

    // O^T accumulators: Oacc[dt] rows d = dt*32 + (r&3)+8*(r>>2)+4*hi, col q=l31
    f16v Oacc[2];
    Oacc[0] = zz; Oacc[1] = zz;
    f4 rs = {0.f, 0.f, 0.f, 0.f};

    // stage K/V chunk at key-offset k0 into buffer p, fragment-major
    auto stage = [&](int k0, int p) {
        #pragma unroll
        for (int it = 0; it < 4; ++it) {
            int c = tid + 256 * it;            // (nt = c>>8, ks = (c>>6)&3, lane)
            int key = k0 + (c >> 8) * 32 + l31;
            int col = ((c >> 6) & 3) * 16 + hi * 8;
            g2lds16(Kb + (size_t)key * 64 + col, &Ks[p][c * 8]);
        }
        #pragma unroll
        for (int it = 0; it < 4; ++it) {
            int c = tid + 256 * it;            // (dt = c>>9, k8 = (c>>6)&7, lane)
            int d   = (c >> 9) * 32 + l31;
            int key = k0 + ((c >> 6) & 7) * 16 + hi * 8;
            g2lds16(Vb + (size_t)d * S_LEN + key, &Vs[p][c * 8]);
        }
    };

    stage(0, 0);

    for (int c = 0; c < S_LEN / 128; ++c) {
        __syncthreads();
        if (c + 1 < S_LEN / 128) stage((c + 1) * 128, (c + 1) & 1);

        const half_t* Kl = Ks[c & 1] + lane * 8;
        const half_t* Vl = Vs[c & 1] + lane * 8;

        // S^T = K * Q^T, four 32-key tiles, K-dim 64 = 4 x 16
        f16v sc[4];
        #pragma unroll
        for (int nt = 0; nt < 4; ++nt) {
            #pragma unroll
            for (int ks = 0; ks < 4; ++ks) {
                h8 kf = *(const h8*)(Kl + nt * 2048 + ks * 512);
                sc[nt] = mfma32(kf, qf[ks], ks == 0 ? zz : sc[nt]);
            }
        }

        // per 32-key group: exp2 -> pack fp16 -> permlane -> PV MFMAs
        #pragma unroll
        for (int nt = 0; nt < 4; ++nt) {
            float p[16];
            #pragma unroll
            for (int r = 0; r < 16; ++r) {
                p[r] = __builtin_amdgcn_exp2f(sc[nt][r]);
                rs[r & 3] += p[r];
            }
            // a[e] = keys {2e,2e+1} of the lane's half (regs 2e,2e+1)
            u32 a0 = pkrtz(p[0],  p[1]);   // k {0,1}  (+4 if hi)
            u32 a1 = pkrtz(p[2],  p[3]);   // k {2,3}
            u32 a2 = pkrtz(p[4],  p[5]);   // k {8,9}
            u32 a3 = pkrtz(p[6],  p[7]);   // k {10,11}
            u32 a4 = pkrtz(p[8],  p[9]);   // k {16,17}
            u32 a5 = pkrtz(p[10], p[11]);  // k {18,19}
            u32 a6 = pkrtz(p[12], p[13]);  // k {24,25}
            u32 a7 = pkrtz(p[14], p[15]);  // k {26,27}

            union H8U { u32 u[4]; h8 v; } b0, b1;
            plswap(a0, a2, b0.u[0], b0.u[2], hi);   // kh=0: k 0..15
            plswap(a1, a3, b0.u[1], b0.u[3], hi);
            plswap(a4, a6, b1.u[0], b1.u[2], hi);   // kh=1: k 16..31
            plswap(a5, a7, b1.u[1], b1.u[3], hi);

            #pragma unroll
            for (int dt = 0; dt < 2; ++dt) {
                h8 vf0 = *(const h8*)(Vl + dt * 4096 + (nt * 2 + 0) * 512);
                h8 vf1 = *(const h8*)(Vl + dt * 4096 + (nt * 2 + 1) * 512);
                Oacc[dt] = mfma32(vf0, b0.v, Oacc[dt]);
                Oacc[dt] = mfma32(vf1, b1.v, Oacc[dt]);
            }
        }
    }

    // row-sum: this lane has half the keys for its q; partner (lane^32) the rest
    float lsum = (rs[0] + rs[1]) + (rs[2] + rs[3]);
    lsum += __shfl_xor(lsum, 32);
    float inv = 1.0f / lsum;

    // epilogue: normalize, write attended [B][S][512]
    const int b = bh >> 3, h = bh & 7;
    half_t* Ob = Oa + ((size_t)(b * S_LEN + q0 + l31)) * DMODEL + h * 64;
    #pragma unroll
    for (int dt = 0; dt < 2; ++dt)
        #pragma unroll
        for (int rg = 0; rg < 4; ++rg) {
            h4 o;
            #pragma unroll
            for (int e = 0; e < 4; ++e) o[e] = (half_t)(Oacc[dt][rg * 4 + e] * inv);
            *(h4*)(Ob + dt * 32 + rg * 8 + hi * 4) = o;
        }
}

// ---------------- launcher ----------------
extern "C" void kernel_launch(void* const* d_in, const int* in_sizes, int n_in,
                              void* d_out, int out_size, void* d_ws, size_t ws_size,
                              hipStream_t stream) {
    const float* X  = (const float*)d_in[0];
    const float* Wq = (const float*)d_in[1];
    const float* Wk = (const float*)d_in[2];
    const float* Wv = (const float*)d_in[3];
    const float* Wc = (const float*)d_in[4];
    const float* bc = (const float*)d_in[5];
    float* out = (float*)d_out;

    char* ws = (char*)d_ws;
    const size_t SZ_X = (size_t)MTOK * DMODEL * 2;     // 8 MB
    const size_t SZ_W = (size_t)DMODEL * DMODEL * 2;   // 512 KB
    half_t* Xh   = (half_t*)(ws);
    half_t* Wqh  = (half_t*)(ws + SZ_X);
    half_t* Wkh  = (half_t*)(ws + SZ_X + SZ_W);
    half_t* Wvh  = (half_t*)(ws + SZ_X + 2 * SZ_W);
    half_t* Wch  = (half_t*)(ws + SZ_X + 3 * SZ_W);
    half_t* Qh   = (half_t*)(ws + SZ_X + 4 * SZ_W);
    half_t* Kh   = (half_t*)(ws + 2 * SZ_X + 4 * SZ_W);
    half_t* Vt   = (half_t*)(ws + 3 * SZ_X + 4 * SZ_W);
    half_t* Att  = (half_t*)(ws + 4 * SZ_X + 4 * SZ_W);

    cvt_all<<<2048 + 512, 256, 0, stream>>>(X, Wq, Wk, Wv, Wc, Xh, Wqh, Wkh, Wvh, Wch);
    gemm_proj<<<dim3(512, 1, 3), 256, 0, stream>>>(Xh, Wqh, Wkh, Wvh, Qh, Kh, Vt);
    flash_attn<<<dim3(32, 16), 256, 0, stream>>>(Qh, Kh, Vt, Att);
    gemm_out<<<512, 256, 0, stream>>>(Att, Wch, bc, out);
}

// Round 13
// 198.932 us; speedup vs baseline: 1.0858x; 1.0858x over previous
//
#include <hip/hip_runtime.h>
#include <cstdint>
#include <cstddef>

typedef _Float16 half_t;
typedef half_t h8 __attribute__((ext_vector_type(8)));
typedef half_t h4 __attribute__((ext_vector_type(4)));
typedef float f4 __attribute__((ext_vector_type(4)));
typedef float f16v __attribute__((ext_vector_type(16)));
typedef unsigned int u32;

static constexpr int S_LEN  = 4096;
static constexpr int DMODEL = 512;
static constexpr int NH     = 8;
static constexpr int HD     = 64;
static constexpr int BATCH  = 2;
static constexpr int MTOK   = BATCH * S_LEN;   // 8192

// 0.125 (1/sqrt(64)) * log2(e): folded into Wq so softmax is pure exp2
#define QSCALE 0.18033688011112043f

// ---------------- async global->LDS (16B per lane) ----------------
__device__ __forceinline__ void g2lds16(const void* g, void* l) {
    __builtin_amdgcn_global_load_lds(
        (const __attribute__((address_space(1))) u32*)(uintptr_t)g,
        (__attribute__((address_space(3))) u32*)(u32)(uintptr_t)l,
        16, 0, 0);
}

__device__ __forceinline__ f4 mfma16(h8 a, h8 b, f4 c) {
    return __builtin_amdgcn_mfma_f32_16x16x32_f16(a, b, c, 0, 0, 0);
}

__device__ __forceinline__ f16v mfma32(h8 a, h8 b, f16v c) {
    return __builtin_amdgcn_mfma_f32_32x32x16_f16(a, b, c, 0, 0, 0);
}

// pack two f32 -> one dword of 2 fp16 (v_cvt_pkrtz_f16_f32)
__device__ __forceinline__ u32 pkrtz(float a, float b) {
#if __has_builtin(__builtin_amdgcn_cvt_pkrtz)
    auto r = __builtin_amdgcn_cvt_pkrtz(a, b);   // __fp16 ext_vector(2)
    return __builtin_bit_cast(u32, r);
#else
    union { half_t h[2]; u32 u; } x;
    x.h[0] = (half_t)a; x.h[1] = (half_t)b;
    return x.u;
#endif
}

// v_permlane32_swap: swaps a's upper 32 lanes with b's lower 32 lanes.
__device__ __forceinline__ void plswap(u32 a, u32 b, u32& lo, u32& hi_, int hi) {
#if __has_builtin(__builtin_amdgcn_permlane32_swap)
    auto r = __builtin_amdgcn_permlane32_swap(a, b, false, false);
    lo = (u32)r[0]; hi_ = (u32)r[1];
#else
    u32 ta = __shfl_xor(a, 32);
    u32 tb = __shfl_xor(b, 32);
    lo  = hi ? tb : a;
    hi_ = hi ? b  : ta;
#endif
}

// ---------------- fp32 -> fp16 converts (X + 4 weights, one launch) --------
__global__ void cvt_all(const float* __restrict__ X,
                        const float* __restrict__ w0, const float* __restrict__ w1,
                        const float* __restrict__ w2, const float* __restrict__ w3,
                        half_t* __restrict__ Xh,
                        half_t* __restrict__ o0, half_t* __restrict__ o1,
                        half_t* __restrict__ o2, half_t* __restrict__ o3) {
    int bx = blockIdx.x;
    const float* in;
    half_t* out;
    float s = 1.0f;
    int i;
    if (bx < 2048) {                       // X: 8192*512 elems
        in = X; out = Xh;
        i = (bx * 256 + threadIdx.x) * 8;
    } else {                               // weights: 512*512 each
        int y = (bx - 2048) >> 7;          // /128
        in  = (y==0) ? w0 : (y==1) ? w1 : (y==2) ? w2 : w3;
        out = (y==0) ? o0 : (y==1) ? o1 : (y==2) ? o2 : o3;
        if (y == 0) s = QSCALE;
        i = (((bx - 2048) & 127) * 256 + threadIdx.x) * 8;
    }
    const float4* p = (const float4*)(in + i);
    float4 a = p[0], b = p[1];
    h8 h;
    h[0]=(half_t)(a.x*s); h[1]=(half_t)(a.y*s); h[2]=(half_t)(a.z*s); h[3]=(half_t)(a.w*s);
    h[4]=(half_t)(b.x*s); h[5]=(half_t)(b.y*s); h[6]=(half_t)(b.z*s); h[7]=(half_t)(b.w*s);
    *(h8*)(out + i) = h;
}

// ------- GEMM core v4: 128x128 tile, BK=32, core2's proven swizzle -------
// C[128x128] = A[M,K] * B[N,K]^T. 4 waves 2x2, wave tile 64x64 (acc[4][4]).
// 16 MFMA : 8 ds_read_b128 per wave per K-step (was 8:6 at 64x128).
// LDS 2x(128x32 A + 128x32 B) = 32 KB double-buffered; one barrier/K-iter.
__device__ __forceinline__ void gemm_core4(const half_t* __restrict__ A,
                                           const half_t* __restrict__ B,
                                           int m0, int n0, int Kdim,
                                           half_t* As, half_t* Bs,   // [2][4096]
                                           f4 (&acc)[4][4]) {
    const int tid  = threadIdx.x;
    const int lane = tid & 63;
    const int w    = tid >> 6;
    const int quad = lane >> 4;
    const int low  = lane & 15;
    const int wr   = (w >> 1) * 64;
    const int wc   = (w & 1) * 64;

    f4 zero = {0.f, 0.f, 0.f, 0.f};
    #pragma unroll
    for (int i = 0; i < 4; ++i)
        #pragma unroll
        for (int j = 0; j < 4; ++j) acc[i][j] = zero;

    auto stage = [&](int kk, int p) {
        #pragma unroll
        for (int it = 0; it < 2; ++it) {   // A: 128 rows x 4 chunks
            int c = tid + 256 * it;
            int row = c >> 2, cs = c & 3;
            int gc = cs ^ ((row >> 1) & 3);
            g2lds16(A + (size_t)(m0 + row) * Kdim + kk + gc * 8, As + p * 4096 + c * 8);
        }
        #pragma unroll
        for (int it = 0; it < 2; ++it) {   // B: 128 rows x 4 chunks
            int c = tid + 256 * it;
            int row = c >> 2, cs = c & 3;
            int gc = cs ^ ((row >> 1) & 3);
            g2lds16(B + (size_t)(n0 + row) * Kdim + kk + gc * 8, Bs + p * 4096 + c * 8);
        }
    };

    stage(0, 0);
    const int T = Kdim / 32;
    for (int t = 0; t < T; ++t) {
        __syncthreads();                    // buf t&1 staged; other buf reusable
        if (t + 1 < T) stage((t + 1) * 32, (t + 1) & 1);

        const half_t* Ac = As + (t & 1) * 4096;
        const half_t* Bc = Bs + (t & 1) * 4096;
        h8 af[4], bf[4];
        #pragma unroll
        for (int i = 0; i < 4; ++i) {
            int r = wr + i * 16 + low;
            af[i] = *(const h8*)(Ac + r * 32 + (quad ^ ((r >> 1) & 3)) * 8);
        }
        #pragma unroll
        for (int j = 0; j < 4; ++j) {
            int r = wc + j * 16 + low;
            bf[j] = *(const h8*)(Bc + r * 32 + (quad ^ ((r >> 1) & 3)) * 8);
        }
        #pragma unroll
        for (int i = 0; i < 4; ++i)
            #pragma unroll
            for (int j = 0; j < 4; ++j)
                acc[i][j] = mfma16(af[i], bf[j], acc[i][j]);
    }
}

// Merged projections: z=0 Q, z=1 K (tokens x d), z=2 V^T (d x tokens).
// z<2: 64 m-tiles x 4 n-tiles; z=2: 4 m-tiles x 64 n-tiles. Grid (256,1,3).
__global__ __launch_bounds__(256, 3) void gemm_proj(
    const half_t* __restrict__ X,
    const half_t* __restrict__ Wq, const half_t* __restrict__ Wk, const half_t* __restrict__ Wv,
    half_t* __restrict__ Q, half_t* __restrict__ K, half_t* __restrict__ Vt) {
    __shared__ half_t As[2 * 128 * 32];
    __shared__ half_t Bs[2 * 128 * 32];
    const int z  = blockIdx.z;
    const int bx = blockIdx.x;

    const half_t *A, *B;
    int m0, n0;
    if (z < 2) {          // C = X · W^T : M=8192 tokens, N=512 d
        A = X; B = (z == 0) ? Wq : Wk;
        m0 = (bx >> 2) * 128; n0 = (bx & 3) * 128;
    } else {              // C = Wv · X^T : M=512 d, N=8192 tokens
        A = Wv; B = X;
        m0 = (bx & 3) * 128; n0 = (bx >> 2) * 128;
    }
    f4 acc[4][4];
    gemm_core4(A, B, m0, n0, DMODEL, As, Bs, acc);

    const int lane = threadIdx.x & 63;
    const int w    = threadIdx.x >> 6;
    const int quad = lane >> 4, low = lane & 15;
    const int wr = (w >> 1) * 64, wc = (w & 1) * 64;

    if (z < 2) {
        half_t* O = (z == 0) ? Q : K;
        #pragma unroll
        for (int i = 0; i < 4; ++i) {
            int mb = m0 + wr + i * 16 + quad * 4;
            #pragma unroll
            for (int j = 0; j < 4; ++j) {
                int n = n0 + wc + j * 16 + low;
                int h = n >> 6, d = n & 63;
                #pragma unroll
                for (int r = 0; r < 4; ++r) {
                    int m = mb + r;
                    int b = m >> 12, s = m & 4095;
                    size_t idx = (((size_t)(b * NH + h) << 12) + s) * 64 + d;
                    O[idx] = (half_t)acc[i][j][r];
                }
            }
        }
    } else {
        #pragma unroll
        for (int i = 0; i < 4; ++i) {
            int dgb = m0 + wr + i * 16 + quad * 4;
            #pragma unroll
            for (int j = 0; j < 4; ++j) {
                int tok = n0 + wc + j * 16 + low;
                int b = tok >> 12, s = tok & 4095;
                #pragma unroll
                for (int r = 0; r < 4; ++r) {
                    int dg = dgb + r;
                    size_t idx = (((size_t)(b * NH + (dg >> 6)) << 18)) + ((dg & 63) << 12) + s;
                    Vt[idx] = (half_t)acc[i][j][r];
                }
            }
        }
    }
}

// Output projection + bias, fp32 out [8192, 512]. 128x128 tiles, 256 blocks.
__global__ __launch_bounds__(256, 3) void gemm_out(
    const half_t* __restrict__ A, const half_t* __restrict__ W,
    const float* __restrict__ bias, float* __restrict__ out) {
    __shared__ half_t As[2 * 128 * 32];
    __shared__ half_t Bs[2 * 128 * 32];
    const int bx = blockIdx.x;
    const int m0 = (bx >> 2) * 128;
    const int n0 = (bx & 3) * 128;
    f4 acc[4][4];
    gemm_core4(A, W, m0, n0, DMODEL, As, Bs, acc);

    const int lane = threadIdx.x & 63;
    const int w    = threadIdx.x >> 6;
    const int quad = lane >> 4, low = lane & 15;
    const int wr = (w >> 1) * 64, wc = (w & 1) * 64;

    #pragma unroll
    for (int i = 0; i < 4; ++i) {
        int mb = m0 + wr + i * 16 + quad * 4;
        #pragma unroll
        for (int j = 0; j < 4; ++j) {
            int n = n0 + wc + j * 16 + low;
            float bv = bias[n];
            #pragma unroll
            for (int r = 0; r < 4; ++r)
                out[(size_t)(mb + r) * DMODEL + n] = acc[i][j][r] + bv;
        }
    }
}

// ---------------- flash attention — EXACT R8-passing kernel ----------------
// 32x32 MFMA, fragment-major K/V LDS (0 bank conflicts, measured), 128-key
// chunks double-buffered, in-register P via cvt_pkrtz + permlane32_swap.
__global__ __launch_bounds__(256, 2) void flash_attn(
    const half_t* __restrict__ Q,   // [BH][S][64]
    const half_t* __restrict__ K,   // [BH][S][64]
    const half_t* __restrict__ V,   // [BH][64][S]  (d-major)
    half_t* __restrict__ Oa) {      // [B][S][512]
    __shared__ half_t Ks[2][128 * 64];   // 2x16 KB fragment-major
    __shared__ half_t Vs[2][64 * 128];   // 2x16 KB fragment-major

    const int tid  = threadIdx.x;
    const int lane = tid & 63;
    const int w    = tid >> 6;
    const int l31  = lane & 31;
    const int hi   = lane >> 5;
    const int bh   = blockIdx.y;
    const int q0   = blockIdx.x * 128 + w * 32;

    const half_t* Qb = Q + ((size_t)bh << 18);
    const half_t* Kb = K + ((size_t)bh << 18);
    const half_t* Vb = V + ((size_t)bh << 18);

    // Q fragments (B-operand of S^T): lane holds q=q0+l31, k=ks*16+hi*8..+7
    h8 qf[4];
    #pragma unroll
    for (int ks = 0; ks < 4; ++ks)
        qf[ks] = *(const h8*)(Qb + (size_t)(q0 + l31) * 64 + ks * 16 + hi * 8);

    f16v zz;
    #pragma unroll
    for (int r = 0; r < 16; ++r) zz[r] = 0.f;

    // O^T accumulators: Oacc[dt] rows d = dt*32 + (r&3)+8*(r>>2)+4*hi, col q=l31
    f16v Oacc[2];
    Oacc[0] = zz; Oacc[1] = zz;
    f4 rs = {0.f, 0.f, 0.f, 0.f};

    // stage K/V chunk at key-offset k0 into buffer p, fragment-major
    auto stage = [&](int k0, int p) {
        #pragma unroll
        for (int it = 0; it < 4; ++it) {
            int c = tid + 256 * it;            // (nt = c>>8, ks = (c>>6)&3, lane)
            int key = k0 + (c >> 8) * 32 + l31;
            int col = ((c >> 6) & 3) * 16 + hi * 8;
            g2lds16(Kb + (size_t)key * 64 + col, &Ks[p][c * 8]);
        }
        #pragma unroll
        for (int it = 0; it < 4; ++it) {
            int c = tid + 256 * it;            // (dt = c>>9, k8 = (c>>6)&7, lane)
            int d   = (c >> 9) * 32 + l31;
            int key = k0 + ((c >> 6) & 7) * 16 + hi * 8;
            g2lds16(Vb + (size_t)d * S_LEN + key, &Vs[p][c * 8]);
        }
    };

    stage(0, 0);

    for (int c = 0; c < S_LEN / 128; ++c) {
        __syncthreads();
        if (c + 1 < S_LEN / 128) stage((c + 1) * 128, (c + 1) & 1);

        const half_t* Kl = Ks[c & 1] + lane * 8;
        const half_t* Vl = Vs[c & 1] + lane * 8;

        // S^T = K * Q^T, four 32-key tiles, K-dim 64 = 4 x 16
        f16v sc[4];
        #pragma unroll
        for (int nt = 0; nt < 4; ++nt) {
            #pragma unroll
            for (int ks = 0; ks < 4; ++ks) {
                h8 kf = *(const h8*)(Kl + nt * 2048 + ks * 512);
                sc[nt] = mfma32(kf, qf[ks], ks == 0 ? zz : sc[nt]);
            }
        }

        // per 32-key group: exp2 -> pack fp16 -> permlane -> PV MFMAs
        #pragma unroll
        for (int nt = 0; nt < 4; ++nt) {
            float p[16];
            #pragma unroll
            for (int r = 0; r < 16; ++r) {
                p[r] = __builtin_amdgcn_exp2f(sc[nt][r]);
                rs[r & 3] += p[r];
            }
            // a[e] = keys {2e,2e+1} of the lane's half (regs 2e,2e+1)
            u32 a0 = pkrtz(p[0],  p[1]);   // k {0,1}  (+4 if hi)
            u32 a1 = pkrtz(p[2],  p[3]);   // k {2,3}
            u32 a2 = pkrtz(p[4],  p[5]);   // k {8,9}
            u32 a3 = pkrtz(p[6],  p[7]);   // k {10,11}
            u32 a4 = pkrtz(p[8],  p[9]);   // k {16,17}
            u32 a5 = pkrtz(p[10], p[11]);  // k {18,19}
            u32 a6 = pkrtz(p[12], p[13]);  // k {24,25}
            u32 a7 = pkrtz(p[14], p[15]);  // k {26,27}

            union H8U { u32 u[4]; h8 v; } b0, b1;
            plswap(a0, a2, b0.u[0], b0.u[2], hi);   // kh=0: k 0..15
            plswap(a1, a3, b0.u[1], b0.u[3], hi);
            plswap(a4, a6, b1.u[0], b1.u[2], hi);   // kh=1: k 16..31
            plswap(a5, a7, b1.u[1], b1.u[3], hi);

            #pragma unroll
            for (int dt = 0; dt < 2; ++dt) {
                h8 vf0 = *(const h8*)(Vl + dt * 4096 + (nt * 2 + 0) * 512);
                h8 vf1 = *(const h8*)(Vl + dt * 4096 + (nt * 2 + 1) * 512);
                Oacc[dt] = mfma32(vf0, b0.v, Oacc[dt]);
                Oacc[dt] = mfma32(vf1, b1.v, Oacc[dt]);
            }
        }
    }

    // row-sum: this lane has half the keys for its q; partner (lane^32) the rest
    float lsum = (rs[0] + rs[1]) + (rs[2] + rs[3]);
    lsum += __shfl_xor(lsum, 32);
    float inv = 1.0f / lsum;

    // epilogue: normalize, write attended [B][S][512]
    const int b = bh >> 3, h = bh & 7;
    half_t* Ob = Oa + ((size_t)(b * S_LEN + q0 + l31)) * DMODEL + h * 64;
    #pragma unroll
    for (int dt = 0; dt < 2; ++dt)
        #pragma unroll
        for (int rg = 0; rg < 4; ++rg) {
            h4 o;
            #pragma unroll
            for (int e = 0; e < 4; ++e) o[e] = (half_t)(Oacc[dt][rg * 4 + e] * inv);
            *(h4*)(Ob + dt * 32 + rg * 8 + hi * 4) = o;
        }
}

// ---------------- launcher ----------------
extern "C" void kernel_launch(void* const* d_in, const int* in_sizes, int n_in,
                              void* d_out, int out_size, void* d_ws, size_t ws_size,
                              hipStream_t stream) {
    const float* X  = (const float*)d_in[0];
    const float* Wq = (const float*)d_in[1];
    const float* Wk = (const float*)d_in[2];
    const float* Wv = (const float*)d_in[3];
    const float* Wc = (const float*)d_in[4];
    const float* bc = (const float*)d_in[5];
    float* out = (float*)d_out;

    char* ws = (char*)d_ws;
    const size_t SZ_X = (size_t)MTOK * DMODEL * 2;     // 8 MB
    const size_t SZ_W = (size_t)DMODEL * DMODEL * 2;   // 512 KB
    half_t* Xh   = (half_t*)(ws);
    half_t* Wqh  = (half_t*)(ws + SZ_X);
    half_t* Wkh  = (half_t*)(ws + SZ_X + SZ_W);
    half_t* Wvh  = (half_t*)(ws + SZ_X + 2 * SZ_W);
    half_t* Wch  = (half_t*)(ws + SZ_X + 3 * SZ_W);
    half_t* Qh   = (half_t*)(ws + SZ_X + 4 * SZ_W);
    half_t* Kh   = (half_t*)(ws + 2 * SZ_X + 4 * SZ_W);
    half_t* Vt   = (half_t*)(ws + 3 * SZ_X + 4 * SZ_W);
    half_t* Att  = (half_t*)(ws + 4 * SZ_X + 4 * SZ_W);

    cvt_all<<<2048 + 512, 256, 0, stream>>>(X, Wq, Wk, Wv, Wc, Xh, Wqh, Wkh, Wvh, Wch);
    gemm_proj<<<dim3(256, 1, 3), 256, 0, stream>>>(Xh, Wqh, Wkh, Wvh, Qh, Kh, Vt);
    flash_attn<<<dim3(32, 16), 256, 0, stream>>>(Qh, Kh, Vt, Att);
    gemm_out<<<256, 256, 0, stream>>>(Att, Wch, bc, out);
}

// Round 14
// 190.726 us; speedup vs baseline: 1.1325x; 1.0430x over previous
//
#include <hip/hip_runtime.h>
#include <cstdint>
#include <cstddef>

typedef _Float16 half_t;
typedef half_t h8 __attribute__((ext_vector_type(8)));
typedef half_t h4 __attribute__((ext_vector_type(4)));
typedef float f4 __attribute__((ext_vector_type(4)));
typedef float f16v __attribute__((ext_vector_type(16)));
typedef unsigned int u32;

static constexpr int S_LEN  = 4096;
static constexpr int DMODEL = 512;
static constexpr int NH     = 8;
static constexpr int HD     = 64;
static constexpr int BATCH  = 2;
static constexpr int MTOK   = BATCH * S_LEN;   // 8192

// 0.125 (1/sqrt(64)) * log2(e): folded into Wq so softmax is pure exp2
#define QSCALE 0.18033688011112043f

// ---------------- async global->LDS (16B per lane) ----------------
__device__ __forceinline__ void g2lds16(const void* g, void* l) {
    __builtin_amdgcn_global_load_lds(
        (const __attribute__((address_space(1))) u32*)(uintptr_t)g,
        (__attribute__((address_space(3))) u32*)(u32)(uintptr_t)l,
        16, 0, 0);
}

__device__ __forceinline__ f4 mfma16(h8 a, h8 b, f4 c) {
    return __builtin_amdgcn_mfma_f32_16x16x32_f16(a, b, c, 0, 0, 0);
}

__device__ __forceinline__ f16v mfma32(h8 a, h8 b, f16v c) {
    return __builtin_amdgcn_mfma_f32_32x32x16_f16(a, b, c, 0, 0, 0);
}

// pack two f32 -> one dword of 2 fp16 (v_cvt_pkrtz_f16_f32)
__device__ __forceinline__ u32 pkrtz(float a, float b) {
#if __has_builtin(__builtin_amdgcn_cvt_pkrtz)
    auto r = __builtin_amdgcn_cvt_pkrtz(a, b);   // __fp16 ext_vector(2)
    return __builtin_bit_cast(u32, r);
#else
    union { half_t h[2]; u32 u; } x;
    x.h[0] = (half_t)a; x.h[1] = (half_t)b;
    return x.u;
#endif
}

// v_permlane32_swap: swaps a's upper 32 lanes with b's lower 32 lanes.
__device__ __forceinline__ void plswap(u32 a, u32 b, u32& lo, u32& hi_, int hi) {
#if __has_builtin(__builtin_amdgcn_permlane32_swap)
    auto r = __builtin_amdgcn_permlane32_swap(a, b, false, false);
    lo = (u32)r[0]; hi_ = (u32)r[1];
#else
    u32 ta = __shfl_xor(a, 32);
    u32 tb = __shfl_xor(b, 32);
    lo  = hi ? tb : a;
    hi_ = hi ? b  : ta;
#endif
}

// ---------------- fp32 -> fp16 converts (X + 4 weights, one launch) --------
__global__ void cvt_all(const float* __restrict__ X,
                        const float* __restrict__ w0, const float* __restrict__ w1,
                        const float* __restrict__ w2, const float* __restrict__ w3,
                        half_t* __restrict__ Xh,
                        half_t* __restrict__ o0, half_t* __restrict__ o1,
                        half_t* __restrict__ o2, half_t* __restrict__ o3) {
    int bx = blockIdx.x;
    const float* in;
    half_t* out;
    float s = 1.0f;
    int i;
    if (bx < 2048) {                       // X: 8192*512 elems
        in = X; out = Xh;
        i = (bx * 256 + threadIdx.x) * 8;
    } else {                               // weights: 512*512 each
        int y = (bx - 2048) >> 7;          // /128
        in  = (y==0) ? w0 : (y==1) ? w1 : (y==2) ? w2 : w3;
        out = (y==0) ? o0 : (y==1) ? o1 : (y==2) ? o2 : o3;
        if (y == 0) s = QSCALE;
        i = (((bx - 2048) & 127) * 256 + threadIdx.x) * 8;
    }
    const float4* p = (const float4*)(in + i);
    float4 a = p[0], b = p[1];
    h8 h;
    h[0]=(half_t)(a.x*s); h[1]=(half_t)(a.y*s); h[2]=(half_t)(a.z*s); h[3]=(half_t)(a.w*s);
    h[4]=(half_t)(b.x*s); h[5]=(half_t)(b.y*s); h[6]=(half_t)(b.z*s); h[7]=(half_t)(b.w*s);
    *(h8*)(out + i) = h;
}

// ------- GEMM core v4: 128x128 tile, BK=32, core2's proven swizzle -------
// C[128x128] = A[M,K] * B[N,K]^T. 4 waves 2x2, wave tile 64x64 (acc[4][4]).
// LDS 2x(128x32 A + 128x32 B) = 32 KB double-buffered; one barrier/K-iter.
__device__ __forceinline__ void gemm_core4(const half_t* __restrict__ A,
                                           const half_t* __restrict__ B,
                                           int m0, int n0, int Kdim,
                                           half_t* As, half_t* Bs,   // [2][4096]
                                           f4 (&acc)[4][4]) {
    const int tid  = threadIdx.x;
    const int lane = tid & 63;
    const int w    = tid >> 6;
    const int quad = lane >> 4;
    const int low  = lane & 15;
    const int wr   = (w >> 1) * 64;
    const int wc   = (w & 1) * 64;

    f4 zero = {0.f, 0.f, 0.f, 0.f};
    #pragma unroll
    for (int i = 0; i < 4; ++i)
        #pragma unroll
        for (int j = 0; j < 4; ++j) acc[i][j] = zero;

    auto stage = [&](int kk, int p) {
        #pragma unroll
        for (int it = 0; it < 2; ++it) {   // A: 128 rows x 4 chunks
            int c = tid + 256 * it;
            int row = c >> 2, cs = c & 3;
            int gc = cs ^ ((row >> 1) & 3);
            g2lds16(A + (size_t)(m0 + row) * Kdim + kk + gc * 8, As + p * 4096 + c * 8);
        }
        #pragma unroll
        for (int it = 0; it < 2; ++it) {   // B: 128 rows x 4 chunks
            int c = tid + 256 * it;
            int row = c >> 2, cs = c & 3;
            int gc = cs ^ ((row >> 1) & 3);
            g2lds16(B + (size_t)(n0 + row) * Kdim + kk + gc * 8, Bs + p * 4096 + c * 8);
        }
    };

    stage(0, 0);
    const int T = Kdim / 32;
    for (int t = 0; t < T; ++t) {
        __syncthreads();                    // buf t&1 staged; other buf reusable
        if (t + 1 < T) stage((t + 1) * 32, (t + 1) & 1);

        const half_t* Ac = As + (t & 1) * 4096;
        const half_t* Bc = Bs + (t & 1) * 4096;
        h8 af[4], bf[4];
        #pragma unroll
        for (int i = 0; i < 4; ++i) {
            int r = wr + i * 16 + low;
            af[i] = *(const h8*)(Ac + r * 32 + (quad ^ ((r >> 1) & 3)) * 8);
        }
        #pragma unroll
        for (int j = 0; j < 4; ++j) {
            int r = wc + j * 16 + low;
            bf[j] = *(const h8*)(Bc + r * 32 + (quad ^ ((r >> 1) & 3)) * 8);
        }
        #pragma unroll
        for (int i = 0; i < 4; ++i)
            #pragma unroll
            for (int j = 0; j < 4; ++j)
                acc[i][j] = mfma16(af[i], bf[j], acc[i][j]);
    }
}

// Merged projections: z=0 Q, z=1 K (tokens x d), z=2 V^T (d x tokens).
// LDS-staged coalesced epilogue: acc -> SM[128][128] fp16 (XOR-swizzled)
// -> 16B h8 stores contiguous along d (z<2) / tokens (z=2).
__global__ __launch_bounds__(256, 3) void gemm_proj(
    const half_t* __restrict__ X,
    const half_t* __restrict__ Wq, const half_t* __restrict__ Wk, const half_t* __restrict__ Wv,
    half_t* __restrict__ Q, half_t* __restrict__ K, half_t* __restrict__ Vt) {
    __shared__ half_t SM[16384];            // 32 KB: core4 dbuf, then C-tile
    const int z  = blockIdx.z;
    const int bx = blockIdx.x;

    const half_t *A, *B;
    int m0, n0;
    if (z < 2) {          // C = X · W^T : M=8192 tokens, N=512 d
        A = X; B = (z == 0) ? Wq : Wk;
        m0 = (bx >> 2) * 128; n0 = (bx & 3) * 128;
    } else {              // C = Wv · X^T : M=512 d, N=8192 tokens
        A = Wv; B = X;
        m0 = (bx & 3) * 128; n0 = (bx >> 2) * 128;
    }
    f4 acc[4][4];
    gemm_core4(A, B, m0, n0, DMODEL, SM, SM + 8192, acc);

    const int tid  = threadIdx.x;
    const int lane = tid & 63;
    const int w    = tid >> 6;
    const int quad = lane >> 4, low = lane & 15;
    const int wr = (w >> 1) * 64, wc = (w & 1) * 64;

    // restage acc into SM as [row 128][col 128] with per-row block swizzle:
    // sblk = (col>>3) ^ (((row>>2)&3)<<1)  (bijective; 2 lanes/bank both sides)
    __syncthreads();                        // K-loop LDS reads complete
    #pragma unroll
    for (int i = 0; i < 4; ++i) {
        #pragma unroll
        for (int j = 0; j < 4; ++j) {
            int coln = wc + j * 16 + low;
            #pragma unroll
            for (int r = 0; r < 4; ++r) {
                int row  = wr + i * 16 + quad * 4 + r;
                int sblk = (coln >> 3) ^ (((row >> 2) & 3) << 1);
                SM[row * 128 + sblk * 8 + (coln & 7)] = (half_t)acc[i][j][r];
            }
        }
    }
    __syncthreads();

    if (z < 2) {
        half_t* O = (z == 0) ? Q : K;
        #pragma unroll
        for (int it = 0; it < 8; ++it) {
            int c = tid + 256 * it;
            int row = c >> 4, blk = c & 15;
            h8 v = *(const h8*)(SM + row * 128 + (blk ^ (((row >> 2) & 3) << 1)) * 8);
            int m = m0 + row, n = n0 + blk * 8;
            int h = n >> 6, d = n & 63;
            int b = m >> 12, s = m & 4095;
            *(h8*)(O + (((size_t)(b * NH + h) << 12) + s) * 64 + d) = v;
        }
    } else {
        #pragma unroll
        for (int it = 0; it < 8; ++it) {
            int c = tid + 256 * it;
            int row = c >> 4, blk = c & 15;
            h8 v = *(const h8*)(SM + row * 128 + (blk ^ (((row >> 2) & 3) << 1)) * 8);
            int dg = m0 + row, tok = n0 + blk * 8;
            int b = tok >> 12, s = tok & 4095;
            *(h8*)(Vt + (((size_t)(b * NH + (dg >> 6))) << 18) + ((size_t)(dg & 63) << 12) + s) = v;
        }
    }
}

// Output projection + bias, fp32 out [8192, 512]. 128x128 tiles, 256 blocks.
__global__ __launch_bounds__(256, 3) void gemm_out(
    const half_t* __restrict__ A, const half_t* __restrict__ W,
    const float* __restrict__ bias, float* __restrict__ out) {
    __shared__ half_t As[2 * 128 * 32];
    __shared__ half_t Bs[2 * 128 * 32];
    const int bx = blockIdx.x;
    const int m0 = (bx >> 2) * 128;
    const int n0 = (bx & 3) * 128;
    f4 acc[4][4];
    gemm_core4(A, W, m0, n0, DMODEL, As, Bs, acc);

    const int lane = threadIdx.x & 63;
    const int w    = threadIdx.x >> 6;
    const int quad = lane >> 4, low = lane & 15;
    const int wr = (w >> 1) * 64, wc = (w & 1) * 64;

    #pragma unroll
    for (int i = 0; i < 4; ++i) {
        int mb = m0 + wr + i * 16 + quad * 4;
        #pragma unroll
        for (int j = 0; j < 4; ++j) {
            int n = n0 + wc + j * 16 + low;
            float bv = bias[n];
            #pragma unroll
            for (int r = 0; r < 4; ++r)
                out[(size_t)(mb + r) * DMODEL + n] = acc[i][j][r] + bv;
        }
    }
}

// ---------------- flash attention — EXACT R8-passing kernel ----------------
// 32x32 MFMA, fragment-major K/V LDS (0 bank conflicts, measured), 128-key
// chunks double-buffered, in-register P via cvt_pkrtz + permlane32_swap.
__global__ __launch_bounds__(256, 2) void flash_attn(
    const half_t* __restrict__ Q,   // [BH][S][64]
    const half_t* __restrict__ K,   // [BH][S][64]
    const half_t* __restrict__ V,   // [BH][64][S]  (d-major)
    half_t* __restrict__ Oa) {      // [B][S][512]
    __shared__ half_t Ks[2][128 * 64];   // 2x16 KB fragment-major
    __shared__ half_t Vs[2][64 * 128];   // 2x16 KB fragment-major

    const int tid  = threadIdx.x;
    const int lane = tid & 63;
    const int w    = tid >> 6;
    const int l31  = lane & 31;
    const int hi   = lane >> 5;
    const int bh   = blockIdx.y;
    const int q0   = blockIdx.x * 128 + w * 32;

    const half_t* Qb = Q + ((size_t)bh << 18);
    const half_t* Kb = K + ((size_t)bh << 18);
    const half_t* Vb = V + ((size_t)bh << 18);

    // Q fragments (B-operand of S^T): lane holds q=q0+l31, k=ks*16+hi*8..+7
    h8 qf[4];
    #pragma unroll
    for (int ks = 0; ks < 4; ++ks)
        qf[ks] = *(const h8*)(Qb + (size_t)(q0 + l31) * 64 + ks * 16 + hi * 8);

    f16v zz;
    #pragma unroll
    for (int r = 0; r < 16; ++r) zz[r] = 0.f;

    // O^T accumulators: Oacc[dt] rows d = dt*32 + (r&3)+8*(r>>2)+4*hi, col q=l31
    f16v Oacc[2];
    Oacc[0] = zz; Oacc[1] = zz;
    f4 rs = {0.f, 0.f, 0.f, 0.f};

    // stage K/V chunk at key-offset k0 into buffer p, fragment-major
    auto stage = [&](int k0, int p) {
        #pragma unroll
        for (int it = 0; it < 4; ++it) {
            int c = tid + 256 * it;            // (nt = c>>8, ks = (c>>6)&3, lane)
            int key = k0 + (c >> 8) * 32 + l31;
            int col = ((c >> 6) & 3) * 16 + hi * 8;
            g2lds16(Kb + (size_t)key * 64 + col, &Ks[p][c * 8]);
        }
        #pragma unroll
        for (int it = 0; it < 4; ++it) {
            int c = tid + 256 * it;            // (dt = c>>9, k8 = (c>>6)&7, lane)
            int d   = (c >> 9) * 32 + l31;
            int key = k0 + ((c >> 6) & 7) * 16 + hi * 8;
            g2lds16(Vb + (size_t)d * S_LEN + key, &Vs[p][c * 8]);
        }
    };

    stage(0, 0);

    for (int c = 0; c < S_LEN / 128; ++c) {
        __syncthreads();
        if (c + 1 < S_LEN / 128) stage((c + 1) * 128, (c + 1) & 1);

        const half_t* Kl = Ks[c & 1] + lane * 8;
        const half_t* Vl = Vs[c & 1] + lane * 8;

        // S^T = K * Q^T, four 32-key tiles, K-dim 64 = 4 x 16
        f16v sc[4];
        #pragma unroll
        for (int nt = 0; nt < 4; ++nt) {
            #pragma unroll
            for (int ks = 0; ks < 4; ++ks) {
                h8 kf = *(const h8*)(Kl + nt * 2048 + ks * 512);
                sc[nt] = mfma32(kf, qf[ks], ks == 0 ? zz : sc[nt]);
            }
        }

        // per 32-key group: exp2 -> pack fp16 -> permlane -> PV MFMAs
        #pragma unroll
        for (int nt = 0; nt < 4; ++nt) {
            float p[16];
            #pragma unroll
            for (int r = 0; r < 16; ++r) {
                p[r] = __builtin_amdgcn_exp2f(sc[nt][r]);
                rs[r & 3] += p[r];
            }
            // a[e] = keys {2e,2e+1} of the lane's half (regs 2e,2e+1)
            u32 a0 = pkrtz(p[0],  p[1]);   // k {0,1}  (+4 if hi)
            u32 a1 = pkrtz(p[2],  p[3]);   // k {2,3}
            u32 a2 = pkrtz(p[4],  p[5]);   // k {8,9}
            u32 a3 = pkrtz(p[6],  p[7]);   // k {10,11}
            u32 a4 = pkrtz(p[8],  p[9]);   // k {16,17}
            u32 a5 = pkrtz(p[10], p[11]);  // k {18,19}
            u32 a6 = pkrtz(p[12], p[13]);  // k {24,25}
            u32 a7 = pkrtz(p[14], p[15]);  // k {26,27}

            union H8U { u32 u[4]; h8 v; } b0, b1;
            plswap(a0, a2, b0.u[0], b0.u[2], hi);   // kh=0: k 0..15
            plswap(a1, a3, b0.u[1], b0.u[3], hi);
            plswap(a4, a6, b1.u[0], b1.u[2], hi);   // kh=1: k 16..31
            plswap(a5, a7, b1.u[1], b1.u[3], hi);

            #pragma unroll
            for (int dt = 0; dt < 2; ++dt) {
                h8 vf0 = *(const h8*)(Vl + dt * 4096 + (nt * 2 + 0) * 512);
                h8 vf1 = *(const h8*)(Vl + dt * 4096 + (nt * 2 + 1) * 512);
                Oacc[dt] = mfma32(vf0, b0.v, Oacc[dt]);
                Oacc[dt] = mfma32(vf1, b1.v, Oacc[dt]);
            }
        }
    }

    // row-sum: this lane has half the keys for its q; partner (lane^32) the rest
    float lsum = (rs[0] + rs[1]) + (rs[2] + rs[3]);
    lsum += __shfl_xor(lsum, 32);
    float inv = 1.0f / lsum;

    // epilogue: normalize, write attended [B][S][512]
    const int b = bh >> 3, h = bh & 7;
    half_t* Ob = Oa + ((size_t)(b * S_LEN + q0 + l31)) * DMODEL + h * 64;
    #pragma unroll
    for (int dt = 0; dt < 2; ++dt)
        #pragma unroll
        for (int rg = 0; rg < 4; ++rg) {
            h4 o;
            #pragma unroll
            for (int e = 0; e < 4; ++e) o[e] = (half_t)(Oacc[dt][rg * 4 + e] * inv);
            *(h4*)(Ob + dt * 32 + rg * 8 + hi * 4) = o;
        }
}

// ---------------- launcher ----------------
extern "C" void kernel_launch(void* const* d_in, const int* in_sizes, int n_in,
                              void* d_out, int out_size, void* d_ws, size_t ws_size,
                              hipStream_t stream) {
    const float* X  = (const float*)d_in[0];
    const float* Wq = (const float*)d_in[1];
    const float* Wk = (const float*)d_in[2];
    const float* Wv = (const float*)d_in[3];
    const float* Wc = (const float*)d_in[4];
    const float* bc = (const float*)d_in[5];
    float* out = (float*)d_out;

    char* ws = (char*)d_ws;
    const size_t SZ_X = (size_t)MTOK * DMODEL * 2;     // 8 MB
    const size_t SZ_W = (size_t)DMODEL * DMODEL * 2;   // 512 KB
    half_t* Xh   = (half_t*)(ws);
    half_t* Wqh  = (half_t*)(ws + SZ_X);
    half_t* Wkh  = (half_t*)(ws + SZ_X + SZ_W);
    half_t* Wvh  = (half_t*)(ws + SZ_X + 2 * SZ_W);
    half_t* Wch  = (half_t*)(ws + SZ_X + 3 * SZ_W);
    half_t* Qh   = (half_t*)(ws + SZ_X + 4 * SZ_W);
    half_t* Kh   = (half_t*)(ws + 2 * SZ_X + 4 * SZ_W);
    half_t* Vt   = (half_t*)(ws + 3 * SZ_X + 4 * SZ_W);
    half_t* Att  = (half_t*)(ws + 4 * SZ_X + 4 * SZ_W);

    cvt_all<<<2048 + 512, 256, 0, stream>>>(X, Wq, Wk, Wv, Wc, Xh, Wqh, Wkh, Wvh, Wch);
    gemm_proj<<<dim3(256, 1, 3), 256, 0, stream>>>(Xh, Wqh, Wkh, Wvh, Qh, Kh, Vt);
    flash_attn<<<dim3(32, 16), 256, 0, stream>>>(Qh, Kh, Vt, Att);
    gemm_out<<<256, 256, 0, stream>>>(Att, Wch, bc, out);
}